// Round 8
// baseline (659.407 us; speedup 1.0000x reference)
//
#include <hip/hip_runtime.h>

#define KH_   10
#define KW_   4
#define W_    64
#define K1_   5120       // C*KH*KW
#define WK_   61
#define JP_   5824       // 91*64
#define NZ    819200
#define KS1   8          // k-split gemm1 (chunk 640, 20 iters of 32; M-split x2)
#define KS2   8          // jp-split gemm2 (chunk ~23 iters of 32)
#define NBLK  736
#define NTHR  256

typedef __attribute__((ext_vector_type(8))) short short8;
typedef __attribute__((ext_vector_type(4))) short short4v;
typedef __attribute__((ext_vector_type(4))) float f32x4;

__device__ __forceinline__ unsigned short f2bf(float f) {
    unsigned int u = __float_as_uint(f);
    return (unsigned short)((u + 0x8000u) >> 16);
}

// ---------------------------------------------------------------------------
// software grid barrier: all NBLK blocks co-resident by construction
// (__launch_bounds__(256,3) -> 3 blocks/CU * 256 CU = 768 >= 736).
// Device-scope atomics + __threadfence = the documented inter-WG sync pattern.
// One counter per barrier instance (no reuse -> no generation/reset races);
// counters zeroed by init_kernel each iteration (workspace is poisoned).
// ---------------------------------------------------------------------------
__device__ __forceinline__ void gridbar(unsigned* bar, int k) {
    __syncthreads();
    if (threadIdx.x == 0) {
        __threadfence();   // release: prior global writes visible device-wide
        unsigned prev = __hip_atomic_fetch_add(&bar[k], 1u, __ATOMIC_ACQ_REL,
                                               __HIP_MEMORY_SCOPE_AGENT);
        if (prev + 1u < (unsigned)NBLK) {
            while (__hip_atomic_load(&bar[k], __ATOMIC_ACQUIRE,
                                     __HIP_MEMORY_SCOPE_AGENT) < (unsigned)NBLK) {
                __builtin_amdgcn_s_sleep(8);
            }
        }
        __threadfence();   // acquire: other blocks' writes now visible
    }
    __syncthreads();
}

__global__ void init_kernel(unsigned* __restrict__ bar) {
    if (threadIdx.x < 8) bar[threadIdx.x] = 0u;
}

// ---------------------------------------------------------------------------
// fused pipeline: pack -> bar -> gemm1 -> bar -> softmax -> bar -> gemm2
//                 -> bar -> reduce.  Phase bodies identical to the verified
//                 5-kernel R5 version; only the launch structure changed.
// ---------------------------------------------------------------------------
__global__ __launch_bounds__(NTHR, 3) void fused_kernel(
        const float* __restrict__ z1, const float* __restrict__ z2,
        unsigned short* __restrict__ Qb2, unsigned short* __restrict__ Z2s,
        unsigned short* __restrict__ X,  unsigned short* __restrict__ Atn2,
        float* __restrict__ Sp, float* __restrict__ Op,
        float* __restrict__ out, unsigned* __restrict__ bar) {
    __shared__ short As[2][64 * 40];   // gemm2 KV^T tile (10.25 KB)
    __shared__ float red2[4];          // softmax cross-wave reduction
    const int bid = blockIdx.x;
    const int t = threadIdx.x;

    // ---------------- phase 1: pack (grid-stride over 5200*256 items) ------
    for (int tid = bid * NTHR + t; tid < 1331200; tid += NBLK * NTHR) {
        if (tid < 102400) {                       // --- Qb2 octs ---
            int ko = tid / 160, i = tid - ko * 160;
            int d0 = ko * 8;
            int c = d0 / 40, rr = d0 - c * 40;
            int kh0 = rr >> 2;                    // even
            int ih = i >> 4, iw = i & 15;
            int a0 = c * 6400 + (ih * KH_ + kh0) * W_ + iw * KW_;
            unsigned short v[8];
#pragma unroll
            for (int s = 0; s < 4; ++s) v[s] = f2bf(z1[a0 + s]);
#pragma unroll
            for (int s = 0; s < 4; ++s) v[4 + s] = f2bf(z1[a0 + W_ + s]);
            *(short8*)(Qb2 + (size_t)tid * 8) = *(short8*)v;
        } else if (tid < 512000) {                // --- Z2s octs ---
            int o = tid - 102400;
            int kw = o / 102400, r8 = o - kw * 102400;
            int e0 = r8 * 8;
            int w0 = e0 & 63, rowbase = e0 - w0;
            unsigned short v[8];
#pragma unroll
            for (int s = 0; s < 8; ++s) v[s] = f2bf(z2[rowbase + min(w0 + s + kw, 63)]);
            *(short8*)(Z2s + (size_t)kw * NZ + e0) = *(short8*)v;
        } else {                                  // --- X octs ---
            int o = tid - 512000;                 // o = (c*100+h)*64 + w
            int w = o & 63, ch = o >> 6;
            int h = ch % 100;
            int ch2 = (h < 99) ? ch + 1 : ch;
            unsigned short v[8];
#pragma unroll
            for (int s = 0; s < 4; ++s) v[s] = f2bf(z2[ch * 64 + min(w + s, 63)]);
#pragma unroll
            for (int s = 0; s < 4; ++s) v[4 + s] = f2bf(z2[ch2 * 64 + min(w + s, 63)]);
            *(short8*)(X + (size_t)o * 8) = *(short8*)v;
        }
    }
    gridbar(bar, 0);

    // ---------------- phase 2: gemm1 (736 blocks = 8 ksp x 92) -------------
    {
        const int ksp = bid / 92;        // 0..7
        const int by  = bid - ksp * 92;  // 0..91
        const int hkt = by >> 1;         // 0..45
        const int mhf = by & 1;          // row half (80 rows each)
        const int hk0 = hkt * 2;
        const int wave = t >> 6, lane = t & 63;
        const int nh = wave;             // 0..3: 32-col strip within 128
        const int l15 = lane & 15, q = lane >> 4;
        (void)wave;

        int band[2], wk[2];
#pragma unroll
        for (int n = 0; n < 2; ++n) {
            int jpn = nh * 32 + n * 16 + l15;
            band[n] = jpn >> 6;
            wk[n]   = jpn & 63;
        }
        int rowA[5];
#pragma unroll
        for (int b = 0; b < 5; ++b) rowA[b] = mhf * 80 + b * 16 + l15;

        f32x4 acc[5][2];
#pragma unroll
        for (int b = 0; b < 5; ++b)
#pragma unroll
            for (int n = 0; n < 2; ++n) acc[b][n] = (f32x4){0.f, 0.f, 0.f, 0.f};

        for (int it = 0; it < 20; ++it) {
            const unsigned short* Ab = Qb2 + ((size_t)(ksp * 80 + it * 4 + q) * 160) * 8;
            short8 af[5], bf[2];
#pragma unroll
            for (int b = 0; b < 5; ++b)
                af[b] = *(const short8*)(Ab + rowA[b] * 8);
            int d0 = ksp * 640 + it * 32 + q * 8;
            unsigned du = (unsigned)d0;
            int c = du / 40u, rr = d0 - c * 40;
            int kh0 = rr >> 2;           // even
            const unsigned short* Bb = X + ((size_t)(c * 100 + hk0 + kh0) * 64) * 8;
#pragma unroll
            for (int n = 0; n < 2; ++n)
                bf[n] = *(const short8*)(Bb + (band[n] * 64 + wk[n]) * 8);
#pragma unroll
            for (int b = 0; b < 5; ++b)
#pragma unroll
                for (int n = 0; n < 2; ++n)
                    acc[b][n] = __builtin_amdgcn_mfma_f32_16x16x32_bf16(af[b], bf[n], acc[b][n], 0, 0, 0);
        }
        float* base = Sp + (size_t)ksp * (160 * JP_);
#pragma unroll
        for (int b = 0; b < 5; ++b) {
            int i0 = mhf * 80 + b * 16 + q * 4;
#pragma unroll
            for (int n = 0; n < 2; ++n) {
                int jg = hkt * 128 + nh * 32 + n * 16 + l15;
                if (jg < JP_) {
#pragma unroll
                    for (int r = 0; r < 4; ++r)
                        base[(size_t)(i0 + r) * JP_ + jg] = acc[b][n][r];
                }
            }
        }
    }
    gridbar(bar, 1);

    // ---------------- phase 3: softmax (blocks 0..159, one q-row each) -----
    if (bid < 160) {
        const int i = bid;
        const int wave = t >> 6, lane = t & 63;
        f32x4 v[6];
        float s = 0.f;
#pragma unroll
        for (int jj = 0; jj < 6; ++jj) {
            int q4 = t + jj * 256;
            f32x4 r = (f32x4){0.f, 0.f, 0.f, 0.f};
            if (q4 < 1456) {
                f32x4 a = (f32x4){0.f, 0.f, 0.f, 0.f};
#pragma unroll
                for (int p = 0; p < KS1; ++p)
                    a += *(const f32x4*)(Sp + (size_t)p * (160 * JP_) + (size_t)i * JP_ + q4 * 4);
                a *= (1.0f / 5120.0f);
                bool pad_hi = (((q4 * 4) & 63) == 60);   // cols 61,62,63 of a band
#pragma unroll
                for (int e = 0; e < 4; ++e) {
                    bool ok = !(pad_hi && e > 0);
                    float x = ok ? __expf(a[e]) : 0.f;
                    r[e] = x;
                    s += x;
                }
            }
            v[jj] = r;
        }
#pragma unroll
        for (int off = 32; off >= 1; off >>= 1) s += __shfl_xor(s, off);
        if (lane == 0) red2[wave] = s;
        __syncthreads();
        float inv = 1.0f / (red2[0] + red2[1] + red2[2] + red2[3]);
#pragma unroll
        for (int jj = 0; jj < 6; ++jj) {
            int q4 = t + jj * 256;
            if (q4 < 1456) {
                short4v u;
                u.x = (short)f2bf(v[jj].x * inv);
                u.y = (short)f2bf(v[jj].y * inv);
                u.z = (short)f2bf(v[jj].z * inv);
                u.w = (short)f2bf(v[jj].w * inv);
                *(short4v*)(Atn2 + ((size_t)(q4 >> 1) * 160 + i) * 8 + (q4 & 1) * 4) = u;
            }
        }
    }
    gridbar(bar, 2);

    // ---------------- phase 4: gemm2 (blocks 0..639 = 8 ksp x 80 dt) -------
    if (bid < 640) {
        const int ksp = bid / 80;        // 0..7
        const int dt  = bid - ksp * 80;  // 0..79
        const int dbase = dt * 64;
        const int it0 = (182 * ksp) >> 3;
        const int it1 = (182 * (ksp + 1)) >> 3;
        const int wave = t >> 6, lane = t & 63;
        const int mh = wave & 1, nh = wave >> 1;   // wave tile 32(d) x 80(i)
        const int l15 = lane & 15, q = lane >> 4;

        const int dl_s = t >> 2, jg_s = t & 3;
        const int d_s = dbase + dl_s;
        const unsigned du_s = (unsigned)d_s;
        const int c_s = du_s / 40u, rr_s = d_s - c_s * 40;
        const int kh_s = rr_s >> 2, kw_s = rr_s & 3;
        const int sbase = kw_s * NZ + c_s * 6400 + kh_s * W_;

        f32x4 acc[2][5];
#pragma unroll
        for (int m = 0; m < 2; ++m)
#pragma unroll
            for (int n = 0; n < 5; ++n) acc[m][n] = (f32x4){0.f, 0.f, 0.f, 0.f};

#define STAGE2(buf, itv) do {                                                  \
            int jp0_ = (itv) * 32 + jg_s * 8;                                  \
            int hk_ = jp0_ >> 6, wk0_ = jp0_ & 63;                             \
            *(short8*)&As[buf][dl_s * 40 + jg_s * 8] =                         \
                *(const short8*)(Z2s + sbase + hk_ * W_ + wk0_);               \
        } while (0)

        STAGE2(0, it0);
        for (int it = it0; it < it1; ++it) {
            int pb = (it - it0) & 1;
            __syncthreads();                       // As[pb] ready
            if (it + 1 < it1) STAGE2(pb ^ 1, it + 1);
            int k0 = it * 32;
            short8 af[2], bf[5];
#pragma unroll
            for (int m = 0; m < 2; ++m)
                af[m] = *(const short8*)&As[pb][(mh * 32 + m * 16 + l15) * 40 + q * 8];
            const unsigned short* Bb = Atn2 + ((size_t)((k0 >> 3) + q) * 160) * 8;
#pragma unroll
            for (int n = 0; n < 5; ++n)
                bf[n] = *(const short8*)(Bb + ((nh * 5 + n) * 16 + l15) * 8);
#pragma unroll
            for (int m = 0; m < 2; ++m)
#pragma unroll
                for (int n = 0; n < 5; ++n)
                    acc[m][n] = __builtin_amdgcn_mfma_f32_16x16x32_bf16(af[m], bf[n], acc[m][n], 0, 0, 0);
        }
#undef STAGE2

        float* base = Op + (size_t)ksp * ((size_t)NZ);
#pragma unroll
        for (int m = 0; m < 2; ++m) {
            int d0 = dbase + mh * 32 + m * 16 + q * 4;
#pragma unroll
            for (int n = 0; n < 5; ++n) {
                int i = (nh * 5 + n) * 16 + l15;
#pragma unroll
                for (int r = 0; r < 4; ++r)
                    base[(size_t)(d0 + r) * 160 + i] = acc[m][n][r];
            }
        }
    }
    gridbar(bar, 3);

    // ---------------- phase 5: reduce (grid-stride over 204800) ------------
    for (int tid = bid * NTHR + t; tid < 204800; tid += NBLK * NTHR) {
        int f = tid * 4;
        f32x4 s = (f32x4){0.f, 0.f, 0.f, 0.f};
#pragma unroll
        for (int p = 0; p < KS2; ++p) s += *(const f32x4*)(Op + (size_t)p * NZ + f);
        int d = f / 160, i0 = f - d * 160;          // x4 block never straddles d
        int c = d / 40, rr = d - c * 40;
        int kh = rr >> 2, kw = rr & 3;
#pragma unroll
        for (int r = 0; r < 4; ++r) {
            int i = i0 + r;
            int ih = i >> 4, iw = i & 15;
            out[c * 6400 + (ih * KH_ + kh) * W_ + iw * KW_ + kw] = s[r];
        }
    }
}

extern "C" void kernel_launch(void* const* d_in, const int* in_sizes, int n_in,
                              void* d_out, int out_size, void* d_ws, size_t ws_size,
                              hipStream_t stream) {
    const float* z1 = (const float*)d_in[0];
    const float* z2 = (const float*)d_in[1];
    float* out = (float*)d_out;

    char* w = (char*)d_ws;
    unsigned short* Qb2  = (unsigned short*)(w);                 // 1,638,400 B
    unsigned short* Z2s  = (unsigned short*)(w + 1638400);       // 6,553,600 B
    unsigned short* X    = (unsigned short*)(w + 8192000);       // 13,107,200 B
    unsigned short* Atn2 = (unsigned short*)(w + 21299200);      // 1,863,680 B
    float* Sp = (float*)(w + 23162880);                          // 29,818,880 B (8 partials)
    float* Op = (float*)(w + 52981760);                          // 26,214,400 B (8 partials)
    unsigned* bar = (unsigned*)(w + 79196160);                   // 32 B barrier state

    init_kernel<<<1, 64, 0, stream>>>(bar);
    fused_kernel<<<NBLK, NTHR, 0, stream>>>(z1, z2, Qb2, Z2s, X, Atn2, Sp, Op, out, bar);
}

// Round 10
// 128.505 us; speedup vs baseline: 5.1314x; 5.1314x over previous
//
#include <hip/hip_runtime.h>

#define KH_   10
#define KW_   4
#define W_    64
#define K1_   5120       // C*KH*KW
#define WK_   61
#define JP_   5824       // 91*64
#define NZ    819200
#define KS1   8          // k-split gemm1 (chunk 640, 20 iters of 32; M-split x2)
#define KS2   8          // jp-split gemm2 (chunk ~23 iters of 32)

typedef __attribute__((ext_vector_type(8))) short short8;
typedef __attribute__((ext_vector_type(4))) short short4v;
typedef __attribute__((ext_vector_type(4))) float f32x4;

__device__ __forceinline__ unsigned short f2bf(float f) {
    unsigned int u = __float_as_uint(f);
    return (unsigned short)((u + 0x8000u) >> 16);
}

// ---------------------------------------------------------------------------
// pack: Qb2 (Q frag layout) + X (gemm1 B).  Z2s moved to smpz_kernel.
//   X fast path (w<=60 && h<99, ~94%): no clamp math -> LLVM merges the 8
//   consecutive dword loads into global_load_dwordx4 pairs.
// ---------------------------------------------------------------------------
__global__ __launch_bounds__(256) void pack_kernel(const float* __restrict__ z1,
                                                   const float* __restrict__ z2,
                                                   unsigned short* __restrict__ Qb2,
                                                   unsigned short* __restrict__ X) {
    int tid = blockIdx.x * 256 + threadIdx.x;   // < 921600
    if (tid < 102400) {                       // --- Qb2 octs (frag layout) ---
        int ko = tid / 160, i = tid - ko * 160;
        int d0 = ko * 8;
        int c = d0 / 40, rr = d0 - c * 40;
        int kh0 = rr >> 2;                    // even
        int ih = i >> 4, iw = i & 15;
        int a0 = c * 6400 + (ih * KH_ + kh0) * W_ + iw * KW_;
        unsigned short v[8];
#pragma unroll
        for (int s = 0; s < 4; ++s) v[s] = f2bf(z1[a0 + s]);
#pragma unroll
        for (int s = 0; s < 4; ++s) v[4 + s] = f2bf(z1[a0 + W_ + s]);
        *(short8*)(Qb2 + (size_t)tid * 8) = *(short8*)v;
    } else {                                  // --- X octs ---
        int o = tid - 102400;                 // o = (c*100+h)*64 + w
        int w = o & 63, ch = o >> 6;
        int h = ch % 100;
        unsigned short v[8];
        if (w <= 60 && h < 99) {              // fast path: no clamping needed
            const float* p0 = z2 + ch * 64 + w;
#pragma unroll
            for (int s = 0; s < 4; ++s) v[s] = f2bf(p0[s]);
#pragma unroll
            for (int s = 0; s < 4; ++s) v[4 + s] = f2bf(p0[64 + s]);
        } else {                              // boundary path (w>60 or h==99)
            int ch2 = (h < 99) ? ch + 1 : ch;
#pragma unroll
            for (int s = 0; s < 4; ++s) v[s] = f2bf(z2[ch * 64 + min(w + s, 63)]);
#pragma unroll
            for (int s = 0; s < 4; ++s) v[4 + s] = f2bf(z2[ch2 * 64 + min(w + s, 63)]);
        }
        *(short8*)(X + (size_t)o * 8) = *(short8*)v;
    }
}

// ---------------------------------------------------------------------------
// GEMM1: no LDS, no barriers. grid (KS1=8, 92) = 736 blocks x 256 thr.
// Block tile 80(m) x 128(j) x 640(k); wave tile 80x32 (acc[5][2]).
// (identical to the measured 128.8us R5 version)
// ---------------------------------------------------------------------------
__global__ __launch_bounds__(256) void gemm1_kernel(const unsigned short* __restrict__ Qb2,
                                                    const unsigned short* __restrict__ X,
                                                    float* __restrict__ Sp) {
    const int t = threadIdx.x;
    const int ksp = blockIdx.x;      // 0..7
    const int by  = blockIdx.y;      // 0..91
    const int hkt = by >> 1;         // 0..45
    const int mhf = by & 1;          // row half (80 rows each)
    const int hk0 = hkt * 2;
    const int wave = t >> 6, lane = t & 63;
    const int nh = wave;             // 0..3: 32-col strip within 128
    const int l15 = lane & 15, q = lane >> 4;

    int band[2], wk[2];
#pragma unroll
    for (int n = 0; n < 2; ++n) {
        int jpn = nh * 32 + n * 16 + l15;
        band[n] = jpn >> 6;
        wk[n]   = jpn & 63;
    }
    int rowA[5];
#pragma unroll
    for (int b = 0; b < 5; ++b) rowA[b] = mhf * 80 + b * 16 + l15;

    f32x4 acc[5][2];
#pragma unroll
    for (int b = 0; b < 5; ++b)
#pragma unroll
        for (int n = 0; n < 2; ++n) acc[b][n] = (f32x4){0.f, 0.f, 0.f, 0.f};

    for (int it = 0; it < 20; ++it) {
        const unsigned short* Ab = Qb2 + ((size_t)(ksp * 80 + it * 4 + q) * 160) * 8;
        short8 af[5], bf[2];
#pragma unroll
        for (int b = 0; b < 5; ++b)
            af[b] = *(const short8*)(Ab + rowA[b] * 8);
        int d0 = ksp * 640 + it * 32 + q * 8;
        unsigned du = (unsigned)d0;
        int c = du / 40u, rr = d0 - c * 40;
        int kh0 = rr >> 2;           // even
        const unsigned short* Bb = X + ((size_t)(c * 100 + hk0 + kh0) * 64) * 8;
#pragma unroll
        for (int n = 0; n < 2; ++n)
            bf[n] = *(const short8*)(Bb + (band[n] * 64 + wk[n]) * 8);
#pragma unroll
        for (int b = 0; b < 5; ++b)
#pragma unroll
            for (int n = 0; n < 2; ++n)
                acc[b][n] = __builtin_amdgcn_mfma_f32_16x16x32_bf16(af[b], bf[n], acc[b][n], 0, 0, 0);
    }
    float* base = Sp + (size_t)ksp * (160 * JP_);
#pragma unroll
    for (int b = 0; b < 5; ++b) {
        int i0 = mhf * 80 + b * 16 + q * 4;
#pragma unroll
        for (int n = 0; n < 2; ++n) {
            int jg = hkt * 128 + nh * 32 + n * 16 + l15;
            if (jg < JP_) {
#pragma unroll
                for (int r = 0; r < 4; ++r)
                    base[(size_t)(i0 + r) * JP_ + jg] = acc[b][n][r];
            }
        }
    }
}

// ---------------------------------------------------------------------------
// smpz: softmax (blocks 0..159, one q-row each, 512 thr) + Z2s packing
// (blocks 160..959) — independent work that fills the CUs softmax leaves
// idle.  Z2s fast path: for w0<56 || kw==0, the 8 clamped scalar loads
// become 8 consecutive dword loads (LLVM merges to dwordx4 pairs).
// ---------------------------------------------------------------------------
__global__ __launch_bounds__(512) void smpz_kernel(const float* __restrict__ z2,
                                                   const float* __restrict__ Sp,
                                                   unsigned short* __restrict__ Atn2,
                                                   unsigned short* __restrict__ Z2s) {
    const int bid = blockIdx.x;
    const int t = threadIdx.x;
    if (bid < 160) {                          // ---- softmax role ----
        const int i = bid;
        const int wave = t >> 6, lane = t & 63;
        __shared__ float red2[8];
        f32x4 v[3];
        float s = 0.f;
#pragma unroll
        for (int jj = 0; jj < 3; ++jj) {
            int q4 = t + jj * 512;
            f32x4 r = (f32x4){0.f, 0.f, 0.f, 0.f};
            if (q4 < 1456) {
                f32x4 a = (f32x4){0.f, 0.f, 0.f, 0.f};
#pragma unroll
                for (int p = 0; p < KS1; ++p)
                    a += *(const f32x4*)(Sp + (size_t)p * (160 * JP_) + (size_t)i * JP_ + q4 * 4);
                a *= (1.0f / 5120.0f);
                bool pad_hi = (((q4 * 4) & 63) == 60);   // cols 61,62,63 of a band
#pragma unroll
                for (int e = 0; e < 4; ++e) {
                    bool ok = !(pad_hi && e > 0);
                    float x = ok ? __expf(a[e]) : 0.f;
                    r[e] = x;
                    s += x;
                }
            }
            v[jj] = r;
        }
#pragma unroll
        for (int off = 32; off >= 1; off >>= 1) s += __shfl_xor(s, off);
        if (lane == 0) red2[wave] = s;
        __syncthreads();
        float inv = 1.0f / (red2[0] + red2[1] + red2[2] + red2[3] +
                            red2[4] + red2[5] + red2[6] + red2[7]);
#pragma unroll
        for (int jj = 0; jj < 3; ++jj) {
            int q4 = t + jj * 512;
            if (q4 < 1456) {
                short4v u;
                u.x = (short)f2bf(v[jj].x * inv);
                u.y = (short)f2bf(v[jj].y * inv);
                u.z = (short)f2bf(v[jj].z * inv);
                u.w = (short)f2bf(v[jj].w * inv);
                *(short4v*)(Atn2 + ((size_t)(q4 >> 1) * 160 + i) * 8 + (q4 & 1) * 4) = u;
            }
        }
    } else {                                  // ---- Z2s-pack role ----
        int o = (bid - 160) * 512 + t;        // 0..409599
        int kw = o / 102400, r8 = o - kw * 102400;
        int e0 = r8 * 8;
        int w0 = e0 & 63, rowbase = e0 - w0;
        unsigned short v[8];
        if (w0 < 56 || kw == 0) {             // fast path: window fits in row
            const float* p = z2 + rowbase + w0 + kw;
#pragma unroll
            for (int s = 0; s < 8; ++s) v[s] = f2bf(p[s]);
        } else {                              // boundary: clamp at col 63
#pragma unroll
            for (int s = 0; s < 8; ++s) v[s] = f2bf(z2[rowbase + min(w0 + s + kw, 63)]);
        }
        *(short8*)(Z2s + (size_t)kw * NZ + e0) = *(short8*)v;
    }
}

// ---------------------------------------------------------------------------
// GEMM2: grid (KS2=8, 80) = 640 blocks x 256 thr; tile 64(d) x 160(i),
// ~23-iter k-loop, DOUBLE-BUFFERED LDS (one barrier per k-iter); attn
// B-frags direct from Atn2 (coalesced). fp32 partials Op; no atomics.
// (identical to the measured 128.8us R5 version)
// ---------------------------------------------------------------------------
__global__ __launch_bounds__(256) void gemm2_kernel(const unsigned short* __restrict__ Atn2,
                                                    const unsigned short* __restrict__ Z2s,
                                                    float* __restrict__ Op) {
    __shared__ short As[2][64 * 40];   // KV^T tile [d_local][jp_local], stride 40 (2-way, free)
    const int t = threadIdx.x;
    const int ksp = blockIdx.x;      // 0..7
    const int dt = blockIdx.y;       // 0..79
    const int dbase = dt * 64;
    const int it0 = (182 * ksp) >> 3;
    const int it1 = (182 * (ksp + 1)) >> 3;
    const int wave = t >> 6, lane = t & 63;
    const int mh = wave & 1, nh = wave >> 1;       // wave tile 32(d) x 80(i)
    const int l15 = lane & 15, q = lane >> 4;

    // staging geometry (one short8 per thread per k-iter)
    const int dl_s = t >> 2, jg_s = t & 3;
    const int d_s = dbase + dl_s;
    const unsigned du_s = (unsigned)d_s;
    const int c_s = du_s / 40u, rr_s = d_s - c_s * 40;
    const int kh_s = rr_s >> 2, kw_s = rr_s & 3;
    const int sbase = kw_s * NZ + c_s * 6400 + kh_s * W_;

    f32x4 acc[2][5];
#pragma unroll
    for (int m = 0; m < 2; ++m)
#pragma unroll
        for (int n = 0; n < 5; ++n) acc[m][n] = (f32x4){0.f, 0.f, 0.f, 0.f};

#define STAGE2(buf, itv) do {                                                  \
        int jp0_ = (itv) * 32 + jg_s * 8;                                      \
        int hk_ = jp0_ >> 6, wk0_ = jp0_ & 63;                                 \
        *(short8*)&As[buf][dl_s * 40 + jg_s * 8] =                             \
            *(const short8*)(Z2s + sbase + hk_ * W_ + wk0_);                   \
    } while (0)

    STAGE2(0, it0);
    for (int it = it0; it < it1; ++it) {
        int pb = (it - it0) & 1;
        __syncthreads();                       // As[pb] ready
        if (it + 1 < it1) STAGE2(pb ^ 1, it + 1);
        int k0 = it * 32;
        short8 af[2], bf[5];
#pragma unroll
        for (int m = 0; m < 2; ++m)
            af[m] = *(const short8*)&As[pb][(mh * 32 + m * 16 + l15) * 40 + q * 8];
        const unsigned short* Bb = Atn2 + ((size_t)((k0 >> 3) + q) * 160) * 8;
#pragma unroll
        for (int n = 0; n < 5; ++n)
            bf[n] = *(const short8*)(Bb + ((nh * 5 + n) * 16 + l15) * 8);
#pragma unroll
        for (int m = 0; m < 2; ++m)
#pragma unroll
            for (int n = 0; n < 5; ++n)
                acc[m][n] = __builtin_amdgcn_mfma_f32_16x16x32_bf16(af[m], bf[n], acc[m][n], 0, 0, 0);
    }
#undef STAGE2

    float* base = Op + (size_t)ksp * ((size_t)NZ);
#pragma unroll
    for (int m = 0; m < 2; ++m) {
        int d0 = dbase + mh * 32 + m * 16 + q * 4;
#pragma unroll
        for (int n = 0; n < 5; ++n) {
            int i = (nh * 5 + n) * 16 + l15;
#pragma unroll
            for (int r = 0; r < 4; ++r)
                base[(size_t)(d0 + r) * 160 + i] = acc[m][n][r];
        }
    }
}

// ---------------------------------------------------------------------------
// reduce: out[c][ih*10+kh][iw*4+kw] = sum_p Op[p][d*160+i]; vectorized x4
// ---------------------------------------------------------------------------
__global__ __launch_bounds__(256) void reduce_kernel(const float* __restrict__ Op,
                                                     float* __restrict__ out) {
    int tid = blockIdx.x * 256 + threadIdx.x;   // < 204800
    int f = tid * 4;
    f32x4 s = (f32x4){0.f, 0.f, 0.f, 0.f};
#pragma unroll
    for (int p = 0; p < KS2; ++p) s += *(const f32x4*)(Op + (size_t)p * NZ + f);
    int d = f / 160, i0 = f - d * 160;          // x4 block never straddles d
    int c = d / 40, rr = d - c * 40;
    int kh = rr >> 2, kw = rr & 3;
#pragma unroll
    for (int r = 0; r < 4; ++r) {
        int i = i0 + r;
        int ih = i >> 4, iw = i & 15;
        out[c * 6400 + (ih * KH_ + kh) * W_ + iw * KW_ + kw] = s[r];
    }
}

extern "C" void kernel_launch(void* const* d_in, const int* in_sizes, int n_in,
                              void* d_out, int out_size, void* d_ws, size_t ws_size,
                              hipStream_t stream) {
    const float* z1 = (const float*)d_in[0];
    const float* z2 = (const float*)d_in[1];
    float* out = (float*)d_out;

    char* w = (char*)d_ws;
    unsigned short* Qb2  = (unsigned short*)(w);                 // 1,638,400 B
    unsigned short* Z2s  = (unsigned short*)(w + 1638400);       // 6,553,600 B
    unsigned short* X    = (unsigned short*)(w + 8192000);       // 13,107,200 B
    unsigned short* Atn2 = (unsigned short*)(w + 21299200);      // 1,863,680 B
    float* Sp = (float*)(w + 23162880);                          // 29,818,880 B (8 partials)
    float* Op = (float*)(w + 52981760);                          // 26,214,400 B (8 partials)

    pack_kernel<<<3600, 256, 0, stream>>>(z1, z2, Qb2, X);
    gemm1_kernel<<<dim3(KS1, 92), 256, 0, stream>>>(Qb2, X, Sp);
    smpz_kernel<<<960, 512, 0, stream>>>(z2, Sp, Atn2, Z2s);
    gemm2_kernel<<<dim3(KS2, 80), 256, 0, stream>>>(Atn2, Z2s, Op);
    reduce_kernel<<<800, 256, 0, stream>>>(Op, out);
}